// Round 15
// baseline (43.714 us; speedup 1.0000x reference)
//
#include <hip/hip_runtime.h>
#include <math.h>

// SurrogateCanny fused kernel, round 14: wave-autonomous, barrier-free.
// R13 (packed f32) regressed: clang scalarized v2f + occupancy fell. Revert.
// R12's stalls were block-level phase-locking (load burst -> barrier -> LDS
// burst). Only cross-thread data is the L/R neighbor column = a lane-neighbor
// exchange. New structure: one wave owns a 62x16 tile (lane = column,
// c_im = x0+lane-1; lanes 0/63 are discarded halo columns). 18 sq rows and
// 16 (gx,gy) stay in registers; L/R via __shfl_up/down. No LDS, no barrier,
// no halo block. All FP expressions verbatim from R12 (passed absmax 0).

constexpr int W = 1024, H = 1024;
constexpr int NXT = 17;          // ceil(1024 / 62) x-tiles

__device__ __forceinline__ void sobel_pair(float a00, float a01, float a02,
                                           float a10, float a12,
                                           float a20, float a21, float a22,
                                           float& gxv, float& gyv) {
  // Factored form, bit-identical to the reference row-major accumulation
  // (verified R8-R12).
  float t1 = 0.5f * (a02 - a00);
  float t2 = t1 - a10;
  float t3 = t2 + a12;
  float t4 = t3 - 0.5f * a20;
  gxv = t4 + 0.5f * a22;
  float p1 = 0.5f * a00 + a01;
  float p2 = p1 + 0.5f * a02;
  float u3 = 0.5f * a20 - p2;
  float u4 = u3 + a21;
  gyv = u4 + 0.5f * a22;
}

// decide() verbatim from R12 (passed absmax 0).
__device__ __forceinline__ float decide(float gxv, float gyv, float sc,
                                        float s0a, float s0b, float s1a, float s1b,
                                        float s2a, float s2b, float s3a, float s3b,
                                        float thr, float thr2) {
#pragma clang fp contract(off)
  const float T1 = 0.19891236737965801f, D1 = 5.0e-5f;
  const float T2 = 0.66817863791929898f, D2 = 7.0e-5f;
  const float T3 = 1.49660576266548901f, D3 = 1.5e-4f;
  const float T4 = 5.02733949212584810f, D4 = 1.2e-3f;

  const float av = fabsf(gyv), bv = fabsf(gxv);
  const float c1 = fmaf(-T1, bv, av);
  const float c2 = fmaf(-T2, bv, av);
  const float c3 = fmaf(-T3, bv, av);
  const float c4 = fmaf(-T4, bv, av);

  const float e1 = fmaf(-D1, bv, fabsf(c1));
  const float e2 = fmaf(-D2, bv, fabsf(c2));
  const float e3 = fmaf(-D3, bv, fabsf(c3));
  const float e4 = fmaf(-D4, bv, fabsf(c4));
  const float emin = fminf(fminf(e1, e2), fminf(e3, e4));
  const bool nearb = emin < 0.0f;

  const unsigned sgn = (__float_as_uint(gyv) ^ __float_as_uint(gxv)) >> 31;

  const float m0 = fmaxf(fmaxf(s0a, s0b), thr2);
  const float m1 = fmaxf(fmaxf(s1a, s1b), thr2);
  const float m2 = fmaxf(fmaxf(s2a, s2b), thr2);
  const float m3 = fmaxf(fmaxf(s3a, s3b), thr2);
  float m;
  if (c1 < 0.0f)      m = m0;
  else if (c2 < 0.0f) m = sgn ? m3 : m1;
  else if (c3 < 0.0f) m = m2;
  else if (c4 < 0.0f) m = sgn ? m1 : m3;
  else                m = m0;

  const float scl = sc * 0.999998f;
  const bool raw  = (sc  > m);
  const bool sure = (scl > m);

  const bool need = nearb || (raw != sure);
  float res = sure ? 1.0f : 0.0f;

  if (__builtin_expect(__any((int)need), 0)) {
    const float C = (float)(360.0 / M_PI);
    float r  = gyv / gxv;
    float t  = atanf(r);
    float u  = t * C;
    float v2 = u + 180.0f;
    float w  = v2 / 45.0f;
    int   kk = (int)rintf(w);
    int   dd = kk & 3;
    float sn1e = (dd == 0) ? s0a : (dd == 1) ? s1a : (dd == 2) ? s2a : s3a;
    float sn2e = (dd == 0) ? s0b : (dd == 1) ? s1b : (dd == 2) ? s2b : s3b;
    float gmc = sqrtf(sc), n1 = sqrtf(sn1e), n2 = sqrtf(sn2e);
    bool keep = (gmc - n1 > 0.0f) && (gmc - n2 > 0.0f) && (gmc - thr > 0.0f);
    float slow = keep ? 1.0f : 0.0f;
    res = need ? slow : res;
  }
  return res;
}

__global__ __launch_bounds__(256)
void canny_kernel(const float* __restrict__ img, const float* __restrict__ thrp,
                  float* __restrict__ out) {
#pragma clang fp contract(off)
  const int tid  = threadIdx.x;
  const int lane = tid & 63;
  const int wid  = tid >> 6;           // 4 independent waves per block
  const int xt = blockIdx.x;           // 0..16
  const int yb = blockIdx.y * 4 + wid; // 0..63
  const int b  = blockIdx.z;
  const int by0  = yb * 16;
  const int c_im = xt * 62 + lane - 1; // owned column; lanes 0/63 = halo
  const float* im = img + (size_t)b * (W * H);
  float* ob       = out + (size_t)b * (W * H);
  const bool edge = (xt == 0) || (xt == NXT - 1) || (yb == 0) || (yb == 63);
  const bool okC  = (unsigned)c_im < 1024u;

  const float thr  = *thrp;
  const float thr2 = thr * thr;

  // ---- load 20 img rows x 3 cols (by0-2 .. by0+17, c_im-1 .. c_im+1) ----
  float vA0, vA1, vA2, vA3, vA4, vA5, vA6, vA7, vA8, vA9;
  float vA10, vA11, vA12, vA13, vA14, vA15, vA16, vA17, vA18, vA19;
  float vB0, vB1, vB2, vB3, vB4, vB5, vB6, vB7, vB8, vB9;
  float vB10, vB11, vB12, vB13, vB14, vB15, vB16, vB17, vB18, vB19;
  float vC0, vC1, vC2, vC3, vC4, vC5, vC6, vC7, vC8, vC9;
  float vC10, vC11, vC12, vC13, vC14, vC15, vC16, vC17, vC18, vC19;
  if (!edge) {
    const float* p = im + (size_t)(by0 - 2) * W + (c_im - 1);
#define LR(J) vA##J = p[(J) * W]; vB##J = p[(J) * W + 1]; vC##J = p[(J) * W + 2];
    LR(0) LR(1) LR(2) LR(3) LR(4) LR(5) LR(6) LR(7) LR(8) LR(9)
    LR(10) LR(11) LR(12) LR(13) LR(14) LR(15) LR(16) LR(17) LR(18) LR(19)
#undef LR
  } else {
    const int cm = min(max(c_im - 1, 0), 1023);
    const int cc = min(max(c_im, 0), 1023);
    const int cp = min(max(c_im + 1, 0), 1023);
    const bool okL = (unsigned)(c_im - 1) < 1024u;
    const bool okR = (unsigned)(c_im + 1) < 1024u;
#define LR(J)                                                                  \
    {                                                                          \
      const int rj = by0 - 2 + (J);                                            \
      const bool rOK = (unsigned)rj < 1024u;   /* wave-uniform */              \
      const int rc = min(max(rj, 0), 1023);                                    \
      const float* rp = im + (size_t)rc * W;                                   \
      const float va = rp[cm], vb = rp[cc], vc = rp[cp];                       \
      vA##J = (rOK && okL) ? va : 0.0f;                                        \
      vB##J = (rOK && okC) ? vb : 0.0f;                                        \
      vC##J = (rOK && okR) ? vc : 0.0f;                                        \
    }
    LR(0) LR(1) LR(2) LR(3) LR(4) LR(5) LR(6) LR(7) LR(8) LR(9)
    LR(10) LR(11) LR(12) LR(13) LR(14) LR(15) LR(16) LR(17) LR(18) LR(19)
#undef LR
  }

  // ---- gm phase: 18 sq rows (k = 0..17; image row by0+k-1), all in regs ----
  float sq0, sq1, sq2, sq3, sq4, sq5, sq6, sq7, sq8;
  float sq9, sq10, sq11, sq12, sq13, sq14, sq15, sq16, sq17;
  float gX1, gX2, gX3, gX4, gX5, gX6, gX7, gX8;
  float gX9, gX10, gX11, gX12, gX13, gX14, gX15, gX16;
  float gY1, gY2, gY3, gY4, gY5, gY6, gY7, gY8;
  float gY9, gY10, gY11, gY12, gY13, gY14, gY15, gY16;
#define GM(K, K1, K2, SQ, SAVE)                                                \
  {                                                                            \
    float gxv, gyv;                                                            \
    sobel_pair(vA##K, vB##K, vC##K, vA##K1, vC##K1, vA##K2, vB##K2, vC##K2,    \
               gxv, gyv);                                                      \
    float s = gxv * gxv + gyv * gyv;                                           \
    if (edge) {                                                                \
      if (((unsigned)(by0 + (K) - 1) >= 1024u) || !okC) s = 0.0f;              \
    }                                                                          \
    SQ = s;                                                                    \
    SAVE;                                                                      \
  }
  GM(0, 1, 2, sq0, (void)0)
  GM(1, 2, 3, sq1, ((gX1 = gxv), (gY1 = gyv)))
  GM(2, 3, 4, sq2, ((gX2 = gxv), (gY2 = gyv)))
  GM(3, 4, 5, sq3, ((gX3 = gxv), (gY3 = gyv)))
  GM(4, 5, 6, sq4, ((gX4 = gxv), (gY4 = gyv)))
  GM(5, 6, 7, sq5, ((gX5 = gxv), (gY5 = gyv)))
  GM(6, 7, 8, sq6, ((gX6 = gxv), (gY6 = gyv)))
  GM(7, 8, 9, sq7, ((gX7 = gxv), (gY7 = gyv)))
  GM(8, 9, 10, sq8, ((gX8 = gxv), (gY8 = gyv)))
  GM(9, 10, 11, sq9, ((gX9 = gxv), (gY9 = gyv)))
  GM(10, 11, 12, sq10, ((gX10 = gxv), (gY10 = gyv)))
  GM(11, 12, 13, sq11, ((gX11 = gxv), (gY11 = gyv)))
  GM(12, 13, 14, sq12, ((gX12 = gxv), (gY12 = gyv)))
  GM(13, 14, 15, sq13, ((gX13 = gxv), (gY13 = gyv)))
  GM(14, 15, 16, sq14, ((gX14 = gxv), (gY14 = gyv)))
  GM(15, 16, 17, sq15, ((gX15 = gxv), (gY15 = gyv)))
  GM(16, 17, 18, sq16, ((gX16 = gxv), (gY16 = gyv)))
  GM(17, 18, 19, sq17, (void)0)
#undef GM

  // ---- L/R neighbor columns via lane shuffles (no LDS, no barrier) ----
#define SHUF(K)                                                                \
  const float L##K = __shfl_up(sq##K, 1);                                      \
  const float R##K = __shfl_down(sq##K, 1);
  SHUF(0) SHUF(1) SHUF(2) SHUF(3) SHUF(4) SHUF(5) SHUF(6) SHUF(7) SHUF(8)
  SHUF(9) SHUF(10) SHUF(11) SHUF(12) SHUF(13) SHUF(14) SHUF(15) SHUF(16) SHUF(17)
#undef SHUF

  // ---- pixel phase: 16 pixels per lane (rows by0 .. by0+15) ----
  // Only lanes 1..62 with a valid column write; halo lanes 0/63 are masked
  // off here (their shuffle-garbage L/R cannot trigger the slow path).
  const bool doSt = (lane >= 1) && (lane <= 62) && okC;
  if (doSt) {
    float* orow = ob + (size_t)by0 * W + c_im;
    // pixel j: sc=sq[j+1]; d0:(R[j+1],L[j+1]) d1:(R[j],L[j+2])
    //          d2:(sq[j],sq[j+2]) d3:(L[j],R[j+2])   (mapping verbatim R12)
#define PIX(J, J1, J2)                                                         \
    orow[(J) * W] = decide(gX##J1, gY##J1, sq##J1, R##J1, L##J1, R##J, L##J2,  \
                           sq##J, sq##J2, L##J, R##J2, thr, thr2);
    PIX(0, 1, 2)
    PIX(1, 2, 3)
    PIX(2, 3, 4)
    PIX(3, 4, 5)
    PIX(4, 5, 6)
    PIX(5, 6, 7)
    PIX(6, 7, 8)
    PIX(7, 8, 9)
    PIX(8, 9, 10)
    PIX(9, 10, 11)
    PIX(10, 11, 12)
    PIX(11, 12, 13)
    PIX(12, 13, 14)
    PIX(13, 14, 15)
    PIX(14, 15, 16)
    PIX(15, 16, 17)
#undef PIX
  }
}

extern "C" void kernel_launch(void* const* d_in, const int* in_sizes, int n_in,
                              void* d_out, int out_size, void* d_ws, size_t ws_size,
                              hipStream_t stream) {
  const float* img = (const float*)d_in[0];
  const float* thr = (const float*)d_in[4];
  float* out = (float*)d_out;
  const int batch = in_sizes[0] / (W * H);

  dim3 grid(NXT, 16, batch);   // 17 x-tiles, 64 y-bands / 4 waves, batch
  canny_kernel<<<grid, dim3(256), 0, stream>>>(img, thr, out);
}

// Round 17
// 36.839 us; speedup vs baseline: 1.1866x; 1.1866x over previous
//
#include <hip/hip_runtime.h>
#include <math.h>

// SurrogateCanny fused kernel, round 16 (= round 15 resubmitted; infra failure).
// R12 (best, 35.7us) + one change: interior row loads via UNALIGNED float4
// (11 x global_load_dwordx4 instead of 33 x global_load_dword + per-row
// 64-bit address adds). R13/R14 macro-restructures both regressed; R12
// structure is the local optimum. All other code verbatim from R12 (absmax 0).

constexpr int W = 1024, H = 1024;
constexpr int TX = 128, TY = 16;         // output tile per block (256 threads)
constexpr int GH = TY + 2, GSTR = 132;   // s2 plane: rows r=-1..16 (idx r+1), cols p=c+1

typedef float f4u __attribute__((ext_vector_type(4), aligned(4)));  // unaligned-ok

__device__ __forceinline__ void sobel_pair(float a00, float a01, float a02,
                                           float a10, float a12,
                                           float a20, float a21, float a22,
                                           float& gxv, float& gyv) {
  // Factored form, bit-identical to the reference row-major accumulation
  // (verified R8-R12).
  float t1 = 0.5f * (a02 - a00);
  float t2 = t1 - a10;
  float t3 = t2 + a12;
  float t4 = t3 - 0.5f * a20;
  gxv = t4 + 0.5f * a22;
  float p1 = 0.5f * a00 + a01;
  float p2 = p1 + 0.5f * a02;
  float u3 = 0.5f * a20 - p2;
  float u4 = u3 + a21;
  gyv = u4 + 0.5f * a22;
}

// Guarded global load (halo path only).
__device__ __forceinline__ float gld(const float* __restrict__ im, int r, int c) {
  const bool ok = ((unsigned)r < 1024u) && ((unsigned)c < 1024u);
  const int rc = min(max(r, 0), 1023);
  const int cc = min(max(c, 0), 1023);
  const float v = im[rc * W + cc];
  return ok ? v : 0.0f;
}

// decide() verbatim from R12 (passed absmax 0).
__device__ __forceinline__ float decide(float gxv, float gyv, float sc,
                                        float s0a, float s0b, float s1a, float s1b,
                                        float s2a, float s2b, float s3a, float s3b,
                                        float thr, float thr2) {
#pragma clang fp contract(off)
  const float T1 = 0.19891236737965801f, D1 = 5.0e-5f;
  const float T2 = 0.66817863791929898f, D2 = 7.0e-5f;
  const float T3 = 1.49660576266548901f, D3 = 1.5e-4f;
  const float T4 = 5.02733949212584810f, D4 = 1.2e-3f;

  const float av = fabsf(gyv), bv = fabsf(gxv);
  const float c1 = fmaf(-T1, bv, av);
  const float c2 = fmaf(-T2, bv, av);
  const float c3 = fmaf(-T3, bv, av);
  const float c4 = fmaf(-T4, bv, av);

  const float e1 = fmaf(-D1, bv, fabsf(c1));
  const float e2 = fmaf(-D2, bv, fabsf(c2));
  const float e3 = fmaf(-D3, bv, fabsf(c3));
  const float e4 = fmaf(-D4, bv, fabsf(c4));
  const float emin = fminf(fminf(e1, e2), fminf(e3, e4));
  const bool nearb = emin < 0.0f;

  const unsigned sgn = (__float_as_uint(gyv) ^ __float_as_uint(gxv)) >> 31;

  const float m0 = fmaxf(fmaxf(s0a, s0b), thr2);
  const float m1 = fmaxf(fmaxf(s1a, s1b), thr2);
  const float m2 = fmaxf(fmaxf(s2a, s2b), thr2);
  const float m3 = fmaxf(fmaxf(s3a, s3b), thr2);
  float m;
  if (c1 < 0.0f)      m = m0;
  else if (c2 < 0.0f) m = sgn ? m3 : m1;
  else if (c3 < 0.0f) m = m2;
  else if (c4 < 0.0f) m = sgn ? m1 : m3;
  else                m = m0;

  const float scl = sc * 0.999998f;
  const bool raw  = (sc  > m);
  const bool sure = (scl > m);

  const bool need = nearb || (raw != sure);
  float res = sure ? 1.0f : 0.0f;

  if (__builtin_expect(__any((int)need), 0)) {
    const float C = (float)(360.0 / M_PI);
    float r  = gyv / gxv;
    float t  = atanf(r);
    float u  = t * C;
    float v2 = u + 180.0f;
    float w  = v2 / 45.0f;
    int   kk = (int)rintf(w);
    int   dd = kk & 3;
    float sn1e = (dd == 0) ? s0a : (dd == 1) ? s1a : (dd == 2) ? s2a : s3a;
    float sn2e = (dd == 0) ? s0b : (dd == 1) ? s1b : (dd == 2) ? s2b : s3b;
    float gmc = sqrtf(sc), n1 = sqrtf(sn1e), n2 = sqrtf(sn2e);
    bool keep = (gmc - n1 > 0.0f) && (gmc - n2 > 0.0f) && (gmc - thr > 0.0f);
    float slow = keep ? 1.0f : 0.0f;
    res = need ? slow : res;
  }
  return res;
}

__global__ __launch_bounds__(256)
void canny_kernel(const float* __restrict__ img, const float* __restrict__ thrp,
                  float* __restrict__ out) {
#pragma clang fp contract(off)
  __shared__ __align__(16) float s_sq[GH][GSTR];   // squared grad magnitude

  const int b   = blockIdx.z;
  const int bx0 = blockIdx.x * TX;
  const int by0 = blockIdx.y * TY;
  const float* im = img + (size_t)b * (W * H);
  float* ob       = out + (size_t)b * (W * H);
  const int tid = threadIdx.x;
  const bool edge = (bx0 == 0) || (bx0 + TX == W) || (by0 == 0) || (by0 + TY == H);

  const int c  = tid & 127;           // owned column (image col bx0+c)
  const int tz = tid >> 7;            // wave-uniform strip id (0 or 1)
  const int k0 = 9 * tz;              // first s_sq row idx this thread computes

  // ---- load 11 rows x 3 cols of img directly from global ----
  // value(j,d) == img[by0 + k0 - 2 + j][bx0 + c - 1 + d], zero outside image.
  float iA0, iB0, iC0, iA1, iB1, iC1, iA2, iB2, iC2, iA3, iB3, iC3;
  float iA4, iB4, iC4, iA5, iB5, iC5, iA6, iB6, iC6, iA7, iB7, iC7;
  float iA8, iB8, iC8, iA9, iB9, iC9, iA10, iB10, iC10;
  if (!edge) {
    const float* p = im + (size_t)(by0 + k0 - 2) * W + (bx0 + c - 1);
#define LOADV(J)                                                               \
    {                                                                          \
      f4u v = *reinterpret_cast<const f4u*>(p + (J) * W);                      \
      iA##J = v.x; iB##J = v.y; iC##J = v.z;                                   \
    }
    LOADV(0) LOADV(1) LOADV(2) LOADV(3) LOADV(4) LOADV(5)
    LOADV(6) LOADV(7) LOADV(8) LOADV(9) LOADV(10)
#undef LOADV
  } else {
    // Cheap edge path (verbatim R12): row validity wave-uniform; column OOB
    // only lanes 0/127 -> clamped addresses + cndmask fixups.
    const int cb = bx0 + c;
    const int ccm1 = max(cb - 1, 0);
    const int ccp1 = min(cb + 1, 1023);
    const bool okL = (cb - 1) >= 0;
    const bool okR = (cb + 1) <= 1023;
    const int r0 = by0 + k0 - 2;
#define LOADROW(J, VA, VB, VC)                                                \
    {                                                                         \
      const int rj = r0 + (J);                                                \
      const bool rOK = (unsigned)rj < 1024u;      /* wave-uniform */          \
      const int rc = min(max(rj, 0), 1023);       /* wave-uniform */          \
      const float* rp = im + (size_t)rc * W;                                  \
      const float va = rp[ccm1], vb = rp[cb], vc = rp[ccp1];                  \
      VA = (rOK && okL) ? va : 0.0f;                                          \
      VB = rOK ? vb : 0.0f;                                                   \
      VC = (rOK && okR) ? vc : 0.0f;                                          \
    }
    LOADROW(0, iA0, iB0, iC0)
    LOADROW(1, iA1, iB1, iC1)
    LOADROW(2, iA2, iB2, iC2)
    LOADROW(3, iA3, iB3, iC3)
    LOADROW(4, iA4, iB4, iC4)
    LOADROW(5, iA5, iB5, iC5)
    LOADROW(6, iA6, iB6, iC6)
    LOADROW(7, iA7, iB7, iC7)
    LOADROW(8, iA8, iB8, iC8)
    LOADROW(9, iA9, iB9, iC9)
    LOADROW(10, iA10, iB10, iC10)
#undef LOADROW
  }

  const int rowim0 = by0 + k0 - 1;    // image row of s_sq idx k0

  float t0, t1, t2, t3, t4, t5, t6, t7, t8;
  float sx0, sx1, sx2, sx3, sx4, sx5, sx6, sx7, sx8;
  float sy0, sy1, sy2, sy3, sy4, sy5, sy6, sy7, sy8;

#define GM_ROW(J, A0, B0, C0, A1, C1, A2, B2, C2, T, SX, SY)                   \
  {                                                                            \
    float gxv, gyv;                                                            \
    sobel_pair(A0, B0, C0, A1, C1, A2, B2, C2, gxv, gyv);                      \
    float sq = gxv * gxv + gyv * gyv;                                          \
    if (edge) { if ((unsigned)(rowim0 + J) >= 1024u) sq = 0.0f; }              \
    s_sq[k0 + J][c + 1] = sq;                                                  \
    T = sq; SX = gxv; SY = gyv;                                                \
  }

  GM_ROW(0, iA0, iB0, iC0, iA1, iC1, iA2, iB2, iC2, t0, sx0, sy0)
  GM_ROW(1, iA1, iB1, iC1, iA2, iC2, iA3, iB3, iC3, t1, sx1, sy1)
  GM_ROW(2, iA2, iB2, iC2, iA3, iC3, iA4, iB4, iC4, t2, sx2, sy2)
  GM_ROW(3, iA3, iB3, iC3, iA4, iC4, iA5, iB5, iC5, t3, sx3, sy3)
  GM_ROW(4, iA4, iB4, iC4, iA5, iC5, iA6, iB6, iC6, t4, sx4, sy4)
  GM_ROW(5, iA5, iB5, iC5, iA6, iC6, iA7, iB7, iC7, t5, sx5, sy5)
  GM_ROW(6, iA6, iB6, iC6, iA7, iC7, iA8, iB8, iC8, t6, sx6, sy6)
  GM_ROW(7, iA7, iB7, iC7, iA8, iC8, iA9, iB9, iC9, t7, sx7, sy7)
  GM_ROW(8, iA8, iB8, iC8, iA9, iC9, iA10, iB10, iC10, t8, sx8, sy8)
#undef GM_ROW

  // halo cols c=-1 (p=0) and c=128 (p=129): rows r=-1..16 -> 36 elements
  if (tid < 36) {
    int rr = tid >> 1;                     // 0..17, gm row r = rr-1
    int r  = rr - 1;
    int cc = (tid & 1) ? 128 : -1;
    int hr = by0 - 2 + rr;                 // image row of window top
    int hc = bx0 + cc;                     // image col of window center
    float gxv, gyv;
    sobel_pair(gld(im, hr, hc - 1),     gld(im, hr, hc),     gld(im, hr, hc + 1),
               gld(im, hr + 1, hc - 1),                      gld(im, hr + 1, hc + 1),
               gld(im, hr + 2, hc - 1), gld(im, hr + 2, hc), gld(im, hr + 2, hc + 1),
               gxv, gyv);
    float sq = gxv * gxv + gyv * gyv;
    if (!((unsigned)(by0 + r) < 1024u && (unsigned)(bx0 + cc) < 1024u)) sq = 0.0f;
    s_sq[rr][cc + 1] = sq;
  }
  __syncthreads();

  // ---- pixel phase: 8-pixel column per thread (verbatim R12) ----
  {
    const float thr  = *thrp;
    const float thr2 = thr * thr;
    const int gb = 8 * tz;
    const float L0 = s_sq[gb + 0][c], R0 = s_sq[gb + 0][c + 2];
    const float L1 = s_sq[gb + 1][c], R1 = s_sq[gb + 1][c + 2];
    const float L2 = s_sq[gb + 2][c], R2 = s_sq[gb + 2][c + 2];
    const float L3 = s_sq[gb + 3][c], R3 = s_sq[gb + 3][c + 2];
    const float L4 = s_sq[gb + 4][c], R4 = s_sq[gb + 4][c + 2];
    const float L5 = s_sq[gb + 5][c], R5 = s_sq[gb + 5][c + 2];
    const float L6 = s_sq[gb + 6][c], R6 = s_sq[gb + 6][c + 2];
    const float L7 = s_sq[gb + 7][c], R7 = s_sq[gb + 7][c + 2];
    const float L8 = s_sq[gb + 8][c], R8 = s_sq[gb + 8][c + 2];
    const float L9 = s_sq[gb + 9][c], R9 = s_sq[gb + 9][c + 2];

    float q0, q1, q2, q3, q4, q5, q6, q7, q8, q9;
    float X0, X1, X2, X3, X4, X5, X6, X7;
    float Y0, Y1, Y2, Y3, Y4, Y5, Y6, Y7;
    if (tz == 0) {
      q0 = t0; q1 = t1; q2 = t2; q3 = t3; q4 = t4;
      q5 = t5; q6 = t6; q7 = t7; q8 = t8;
      q9 = s_sq[9][c + 1];
      X0 = sx1; X1 = sx2; X2 = sx3; X3 = sx4; X4 = sx5; X5 = sx6; X6 = sx7; X7 = sx8;
      Y0 = sy1; Y1 = sy2; Y2 = sy3; Y3 = sy4; Y4 = sy5; Y5 = sy6; Y6 = sy7; Y7 = sy8;
    } else {
      q0 = s_sq[8][c + 1];
      q1 = t0; q2 = t1; q3 = t2; q4 = t3; q5 = t4;
      q6 = t5; q7 = t6; q8 = t7; q9 = t8;
      X0 = sx0; X1 = sx1; X2 = sx2; X3 = sx3; X4 = sx4; X5 = sx5; X6 = sx6; X7 = sx7;
      Y0 = sy0; Y1 = sy1; Y2 = sy2; Y3 = sy3; Y4 = sy4; Y5 = sy5; Y6 = sy6; Y7 = sy7;
    }

    float* orow = ob + (size_t)(by0 + gb) * W + bx0 + c;

    // pixel k: sc=q[k+1]; d0:(R[k+1],L[k+1]) d1:(R[k],L[k+2])
    //          d2:(q[k],q[k+2]) d3:(L[k],R[k+2])
    orow[0 * W] = decide(X0, Y0, q1, R1, L1, R0, L2, q0, q2, L0, R2, thr, thr2);
    orow[1 * W] = decide(X1, Y1, q2, R2, L2, R1, L3, q1, q3, L1, R3, thr, thr2);
    orow[2 * W] = decide(X2, Y2, q3, R3, L3, R2, L4, q2, q4, L2, R4, thr, thr2);
    orow[3 * W] = decide(X3, Y3, q4, R4, L4, R3, L5, q3, q5, L3, R5, thr, thr2);
    orow[4 * W] = decide(X4, Y4, q5, R5, L5, R4, L6, q4, q6, L4, R6, thr, thr2);
    orow[5 * W] = decide(X5, Y5, q6, R6, L6, R5, L7, q5, q7, L5, R7, thr, thr2);
    orow[6 * W] = decide(X6, Y6, q7, R7, L7, R6, L8, q6, q8, L6, R8, thr, thr2);
    orow[7 * W] = decide(X7, Y7, q8, R8, L8, R7, L9, q7, q9, L7, R9, thr, thr2);
  }
}

extern "C" void kernel_launch(void* const* d_in, const int* in_sizes, int n_in,
                              void* d_out, int out_size, void* d_ws, size_t ws_size,
                              hipStream_t stream) {
  const float* img = (const float*)d_in[0];
  const float* thr = (const float*)d_in[4];
  float* out = (float*)d_out;
  const int batch = in_sizes[0] / (W * H);

  dim3 grid(W / TX, H / TY, batch);
  canny_kernel<<<grid, dim3(256), 0, stream>>>(img, thr, out);
}